// Round 11
// baseline (1046.618 us; speedup 1.0000x reference)
//
#include <hip/hip_runtime.h>
#include <hip/hip_bf16.h>
#include <stdint.h>

// ---------------------------------------------------------------------------
// LoRALinear: y = x @ (W + B@A)^T + (b + lora_bias)
// M=8192, N=4096, K=4096.
// R11: 4-wave / register-double-buffered GEMM. 256x256 tile, BK=64,
// 4 waves (2Mx2N), per-wave 128x128, acc[8][8] (256 AGPR, 1 wave/SIMD via
// __launch_bounds__(256,1) -> 512-reg unified budget). Operand regs
// A0/B0/A1/B1 double-buffer so each wave issues next ds_reads BEFORE its
// 64-MFMA burst -> LDS drains UNDER MFMA within the wave (m97-asm pattern).
// One barrier per K-tile: burst0; lgkm0; vmcnt0; BAR(all reads of t done +
// t+1 published); stage(t+2); issue reads(t+1,kk0); burst1; lgkm0; reads kk1.
// R4 lesson: 8 waves cap at 256 regs/wave -> no reg-dbuf possible there.
// R5 lesson: publication = drain-then-barrier before cross-wave LDS reads.
// R10 lesson: barrier-locked waves can't overlap LDS/MFMA across waves;
//             overlap must come from WITHIN the wave (reg dbuf).
// ---------------------------------------------------------------------------

#define M_DIM 8192
#define N_DIM 4096
#define K_DIM 4096
#define NT    (K_DIM / 64)   // 64 K-tiles

typedef __attribute__((ext_vector_type(8))) short bf16x8;
typedef __attribute__((ext_vector_type(4))) float f32x4;

#define BARRIER() __builtin_amdgcn_s_barrier()
#define WAITV16() asm volatile("s_waitcnt vmcnt(16)" ::: "memory")
#define WAITV0()  asm volatile("s_waitcnt vmcnt(0)" ::: "memory")
#define LGKM0()   do { asm volatile("s_waitcnt lgkmcnt(0)" ::: "memory"); \
                       __builtin_amdgcn_sched_barrier(0); } while (0)
#define SCHED_FENCE() __builtin_amdgcn_sched_barrier(0)

static __device__ __forceinline__ unsigned short f2bf(float f) {
    unsigned int u = __builtin_bit_cast(unsigned int, f);
    unsigned int r = (u + 0x7fffu + ((u >> 16) & 1u)) >> 16;
    return (unsigned short)r;
}

// --- conv_x: bf16(x) --------------------------------------------------------
__global__ __launch_bounds__(256) void conv_x_kernel(
    const float* __restrict__ x, unsigned short* __restrict__ xb) {
    size_t i = ((size_t)blockIdx.x * 256 + threadIdx.x) * 8;
    float4 a = *(const float4*)(x + i);
    float4 c = *(const float4*)(x + i + 4);
    union { unsigned short us[8]; uint4 v; } u;
    u.us[0] = f2bf(a.x); u.us[1] = f2bf(a.y); u.us[2] = f2bf(a.z); u.us[3] = f2bf(a.w);
    u.us[4] = f2bf(c.x); u.us[5] = f2bf(c.y); u.us[6] = f2bf(c.z); u.us[7] = f2bf(c.w);
    *(uint4*)(xb + i) = u.v;
}

// --- conv_w: bf16(W + B@A). 4 rows/block, lA read once per block. ----------
__global__ __launch_bounds__(512) void conv_w_kernel(
    const float* __restrict__ W, const float* __restrict__ lA,
    const float* __restrict__ lB, unsigned short* __restrict__ Wb) {
    const int nb = blockIdx.x * 4;        // 1024 blocks
    const int k0 = threadIdx.x * 8;       // 512 thr * 8 = 4096

    float acc[4][8];
#pragma unroll
    for (int r = 0; r < 4; ++r) {
        const float4* w4 = (const float4*)(W + (size_t)(nb + r) * K_DIM + k0);
        float4 v0 = w4[0], v1 = w4[1];
        acc[r][0] = v0.x; acc[r][1] = v0.y; acc[r][2] = v0.z; acc[r][3] = v0.w;
        acc[r][4] = v1.x; acc[r][5] = v1.y; acc[r][6] = v1.z; acc[r][7] = v1.w;
    }
    float brs[4][16];
#pragma unroll
    for (int r = 0; r < 4; ++r)
#pragma unroll
        for (int t = 0; t < 16; ++t) brs[r][t] = lB[(size_t)(nb + r) * 16 + t];

#pragma unroll
    for (int t = 0; t < 16; ++t) {
        const float4* a4 = (const float4*)(lA + (size_t)t * K_DIM + k0);
        float4 v0 = a4[0], v1 = a4[1];
        float av[8] = {v0.x, v0.y, v0.z, v0.w, v1.x, v1.y, v1.z, v1.w};
#pragma unroll
        for (int r = 0; r < 4; ++r)
#pragma unroll
            for (int j = 0; j < 8; ++j) acc[r][j] += brs[r][t] * av[j];
    }
#pragma unroll
    for (int r = 0; r < 4; ++r) {
        union { unsigned short us[8]; uint4 v; } u;
#pragma unroll
        for (int j = 0; j < 8; ++j) u.us[j] = f2bf(acc[r][j]);
        *(uint4*)(Wb + (size_t)(nb + r) * K_DIM + k0) = u.v;
    }
}

// --- gemm: 256x256 tile, BK=64, 4 waves, register-dbuf 1-barrier loop -------
__global__ __launch_bounds__(256, 1) void gemm_kernel(
    const unsigned short* __restrict__ A,   // [8192][4096] bf16
    const unsigned short* __restrict__ B,   // [4096][4096] bf16 (W')
    const float* __restrict__ bvec, const float* __restrict__ lbvec,
    float* __restrict__ C) {
    const int tid = threadIdx.x;
    const int lane = tid & 63;
    const int wid = tid >> 6;        // 0..3
    const int wr = wid >> 1;         // 0..1  M-half (128 rows)
    const int wc = wid & 1;          // 0..1  N-half (128 cols)

    // XCD-column-resident mapping (R7): XCD = bid&7 owns 2 ntile columns.
    const int bid = blockIdx.x;
    const int ntile = (bid & 7) * 2 + ((bid >> 3) & 1);  // 0..15
    const int mtile = bid >> 4;                          // 0..31
    const int m0 = mtile * 256, n0 = ntile * 256;

    __shared__ __align__(16) unsigned short ldsA[2 * 2 * 128 * 64];  // 64 KiB
    __shared__ __align__(16) unsigned short ldsB[2 * 2 * 128 * 64];  // 64 KiB

    // --- staging: linear LDS dest, inverse-swizzled global src (T2) ---
    const int lr8 = lane >> 3;             // 0..7
    const int cch = (lane & 7) ^ lr8;      // swizzled 16B-chunk index
    const unsigned short* aSb = A + (size_t)(m0 + lr8) * K_DIM + cch * 8;
    const unsigned short* bSb = B + (size_t)(n0 + lr8) * K_DIM + cch * 8;

    // 4 waves x 4 chunks cover one 128-row half-tile (16 x 1KB chunks).
    auto stageA = [&](int par_, int h, int kt) {
#pragma unroll
        for (int s = 0; s < 4; ++s) {
            const int j = wid * 4 + s;       // 0..15
            const unsigned short* g = aSb + (size_t)(h * 128 + j * 8) * K_DIM + kt * 64;
            __builtin_amdgcn_global_load_lds(
                (const __attribute__((address_space(1))) void*)g,
                (__attribute__((address_space(3))) void*)(ldsA + (par_ * 2 + h) * 8192 + j * 512),
                16, 0, 0);
        }
    };
    auto stageB = [&](int par_, int h, int kt) {
#pragma unroll
        for (int s = 0; s < 4; ++s) {
            const int j = wid * 4 + s;
            const unsigned short* g = bSb + (size_t)(h * 128 + j * 8) * K_DIM + kt * 64;
            __builtin_amdgcn_global_load_lds(
                (const __attribute__((address_space(1))) void*)g,
                (__attribute__((address_space(3))) void*)(ldsB + (par_ * 2 + h) * 8192 + j * 512),
                16, 0, 0);
        }
    };
    auto stageTile = [&](int par_, int kt) {   // 16 loads/thread
        stageB(par_, 0, kt); stageB(par_, 1, kt);
        stageA(par_, 0, kt); stageA(par_, 1, kt);
    };

    // --- read side (T2 swizzle) ---
    const int rowByte = (lane & 15) * 128;
    const int swz = (lane & 7) << 4;
    const int kc0 = (0 * 64 + (lane >> 4) * 16) ^ swz;
    const int kc1 = (1 * 64 + (lane >> 4) * 16) ^ swz;

    auto readA = [&](int par_, int mf, int kk) -> bf16x8 {
        const char* p = (const char*)(ldsA + (par_ * 2 + wr) * 8192 + mf * 1024) +
                        rowByte + (kk ? kc1 : kc0);
        return *(const bf16x8*)p;
    };
    auto readB = [&](int par_, int nf, int kk) -> bf16x8 {
        const char* p = (const char*)(ldsB + (par_ * 2 + wc) * 8192 + nf * 1024) +
                        rowByte + (kk ? kc1 : kc0);
        return *(const bf16x8*)p;
    };

    f32x4 acc[8][8] = {};                    // 256 regs -> AGPR (1 wave/SIMD)
    bf16x8 A0[8], B0[8], A1[8], B1[8];       // 128 VGPR operand double-buffer

    // --- prologue ---
    stageTile(0, 0);
    stageTile(1, 1);
    WAITV16();              // t0 drained (t1 in flight)
    BARRIER();              // publish t0
#pragma unroll
    for (int mf = 0; mf < 8; ++mf) A0[mf] = readA(0, mf, 0);
#pragma unroll
    for (int nf = 0; nf < 8; ++nf) B0[nf] = readB(0, nf, 0);
    LGKM0();                // buf0(t0) ready
#pragma unroll
    for (int mf = 0; mf < 8; ++mf) A1[mf] = readA(0, mf, 1);
#pragma unroll
    for (int nf = 0; nf < 8; ++nf) B1[nf] = readB(0, nf, 1);
    SCHED_FENCE();          // group1 issued before burst0

#pragma unroll 1
    for (int kt = 0; kt < NT; ++kt) {
        const int par = kt & 1;
        // burst0: 64 MFMA on buf0 (kk=0); group1(t) drains underneath
        __builtin_amdgcn_s_setprio(1);
#pragma unroll
        for (int i = 0; i < 8; ++i)
#pragma unroll
            for (int j = 0; j < 8; ++j)
                acc[i][j] = __builtin_amdgcn_mfma_f32_16x16x32_bf16(
                    A0[i], B0[j], acc[i][j], 0, 0, 0);
        __builtin_amdgcn_s_setprio(0);
        LGKM0();            // group1(t) reads complete
        WAITV0();           // t+1 staging landed (issued last KT, ~2700cy ago)
        BARRIER();          // ALL waves done reading t; t+1 published
        if (kt + 2 < NT) stageTile(par, kt + 2);   // overwrite par(t): safe
        if (kt + 1 < NT) {
#pragma unroll
            for (int mf = 0; mf < 8; ++mf) A0[mf] = readA(par ^ 1, mf, 0);
#pragma unroll
            for (int nf = 0; nf < 8; ++nf) B0[nf] = readB(par ^ 1, nf, 0);
        }
        SCHED_FENCE();      // reads+stage issued before burst1
        // burst1: 64 MFMA on buf1 (kk=1); group0(t+1) drains underneath
        __builtin_amdgcn_s_setprio(1);
#pragma unroll
        for (int i = 0; i < 8; ++i)
#pragma unroll
            for (int j = 0; j < 8; ++j)
                acc[i][j] = __builtin_amdgcn_mfma_f32_16x16x32_bf16(
                    A1[i], B1[j], acc[i][j], 0, 0, 0);
        __builtin_amdgcn_s_setprio(0);
        LGKM0();            // buf0(t+1) ready
        if (kt + 1 < NT) {
#pragma unroll
            for (int mf = 0; mf < 8; ++mf) A1[mf] = readA(par ^ 1, mf, 1);
#pragma unroll
            for (int nf = 0; nf < 8; ++nf) B1[nf] = readB(par ^ 1, nf, 1);
        }
        SCHED_FENCE();      // group1(t+1) issued before next burst0
    }

    // --- epilogue: C = acc + (b + lora_bias); NT stores ---
#pragma unroll
    for (int nf = 0; nf < 8; ++nf) {
        const int gc = n0 + wc * 128 + nf * 16 + (lane & 15);
        const float bv = bvec[gc] + lbvec[gc];
#pragma unroll
        for (int mf = 0; mf < 8; ++mf) {
            const int gr0 = m0 + wr * 128 + mf * 16 + (lane >> 4) * 4;
            f32x4 v = acc[mf][nf];
#pragma unroll
            for (int j = 0; j < 4; ++j)
                __builtin_nontemporal_store(v[j] + bv, &C[(size_t)(gr0 + j) * N_DIM + gc]);
        }
    }
}

// --- Fallback: naive fp32 (only if ws too small) ----------------------------
__global__ __launch_bounds__(256) void naive_kernel(
    const float* __restrict__ x, const float* __restrict__ W,
    const float* __restrict__ b, const float* __restrict__ lA,
    const float* __restrict__ lB, const float* __restrict__ lb,
    float* __restrict__ out) {
    __shared__ float xs[K_DIM];
    __shared__ float ts[16];
    const int m = blockIdx.x;
    const int tid = threadIdx.x;
    for (int k = tid; k < K_DIM; k += 256) xs[k] = x[(size_t)m * K_DIM + k];
    if (tid < 16) ts[tid] = 0.f;
    __syncthreads();
    float part[16] = {};
    for (int k = tid * 16; k < tid * 16 + 16; ++k) {
        float xv = xs[k];
#pragma unroll
        for (int r = 0; r < 16; ++r) part[r] += xv * lA[(size_t)r * K_DIM + k];
    }
#pragma unroll
    for (int r = 0; r < 16; ++r) atomicAdd(&ts[r], part[r]);
    __syncthreads();
    const int n = blockIdx.y * 256 + tid;
    float acc = b[n] + lb[n];
#pragma unroll
    for (int r = 0; r < 16; ++r) acc += ts[r] * lB[(size_t)n * 16 + r];
    const float* wrow = W + (size_t)n * K_DIM;
    for (int k = 0; k < K_DIM; ++k) acc += xs[k] * wrow[k];
    out[(size_t)m * N_DIM + n] = acc;
}

// ---------------------------------------------------------------------------
extern "C" void kernel_launch(void* const* d_in, const int* in_sizes, int n_in,
                              void* d_out, int out_size, void* d_ws, size_t ws_size,
                              hipStream_t stream) {
    const float* x  = (const float*)d_in[0];
    const float* W  = (const float*)d_in[1];
    const float* b  = (const float*)d_in[2];
    const float* lA = (const float*)d_in[3];
    const float* lB = (const float*)d_in[4];
    const float* lb = (const float*)d_in[5];
    float* out = (float*)d_out;

    const size_t xb_bytes = (size_t)M_DIM * K_DIM * 2;  // 64 MiB
    const size_t wb_bytes = (size_t)N_DIM * K_DIM * 2;  // 32 MiB

    if (ws_size >= xb_bytes + wb_bytes) {
        unsigned short* xb = (unsigned short*)d_ws;
        unsigned short* wb = (unsigned short*)((char*)d_ws + xb_bytes);

        conv_x_kernel<<<(M_DIM * K_DIM) / (256 * 8), 256, 0, stream>>>(x, xb);
        conv_w_kernel<<<N_DIM / 4, 512, 0, stream>>>(W, lA, lB, wb);

        gemm_kernel<<<(M_DIM / 256) * (N_DIM / 256), 256, 0, stream>>>(xb, wb, b, lb, out);
    } else {
        dim3 grid(M_DIM, N_DIM / 256);
        naive_kernel<<<grid, 256, 0, stream>>>(x, W, b, lA, lB, lb, out);
    }
}

// Round 12
// 332.604 us; speedup vs baseline: 3.1467x; 3.1467x over previous
//
#include <hip/hip_runtime.h>
#include <hip/hip_bf16.h>
#include <stdint.h>

// ---------------------------------------------------------------------------
// LoRALinear: y = x @ (W + B@A)^T + (b + lora_bias)
// M=8192, N=4096, K=4096.
// R12: R10 staging/publication structure + 32x32x16 MFMA core with a 2-deep
// k-step pipeline using counted lgkmcnt(6): each wave's next-kstep ds_reads
// drain under its current 8-MFMA burst; 2 barriers per K-tile.
//  - 32x32x16: 2066 cyc/KT MFMA floor (vs 2483), half the instructions.
//  - operand sets 24 regs -> 2-deep pipeline fits: acc128+48+addr < 256.
// R4/R11 lesson: ~250 regs/wave hard cap; acc[8][8] spills (4.4GB scratch).
// R5 lesson: publication = drain-then-barrier before cross-wave LDS reads.
// R10 lesson: drain-then-burst works; barrier-locked phases still serialize
//             LDS vs MFMA windows -> pipeline WITHIN the wave instead.
// ---------------------------------------------------------------------------

#define M_DIM 8192
#define N_DIM 4096
#define K_DIM 4096
#define NT    (K_DIM / 64)   // 64 K-tiles

typedef __attribute__((ext_vector_type(8)))  short bf16x8;
typedef __attribute__((ext_vector_type(16))) float f32x16;

#define BARRIER() __builtin_amdgcn_s_barrier()
#define WAITV8() asm volatile("s_waitcnt vmcnt(8)" ::: "memory")
#define WAITV0() asm volatile("s_waitcnt vmcnt(0)" ::: "memory")
#define LGKMC(n) asm volatile("s_waitcnt lgkmcnt(" #n ")" ::: "memory")
#define SCHED_FENCE() __builtin_amdgcn_sched_barrier(0)

static __device__ __forceinline__ unsigned short f2bf(float f) {
    unsigned int u = __builtin_bit_cast(unsigned int, f);
    unsigned int r = (u + 0x7fffu + ((u >> 16) & 1u)) >> 16;
    return (unsigned short)r;
}

// --- conv_x: bf16(x) --------------------------------------------------------
__global__ __launch_bounds__(256) void conv_x_kernel(
    const float* __restrict__ x, unsigned short* __restrict__ xb) {
    size_t i = ((size_t)blockIdx.x * 256 + threadIdx.x) * 8;
    float4 a = *(const float4*)(x + i);
    float4 c = *(const float4*)(x + i + 4);
    union { unsigned short us[8]; uint4 v; } u;
    u.us[0] = f2bf(a.x); u.us[1] = f2bf(a.y); u.us[2] = f2bf(a.z); u.us[3] = f2bf(a.w);
    u.us[4] = f2bf(c.x); u.us[5] = f2bf(c.y); u.us[6] = f2bf(c.z); u.us[7] = f2bf(c.w);
    *(uint4*)(xb + i) = u.v;
}

// --- conv_w: bf16(W + B@A). 4 rows/block, lA read once per block. ----------
__global__ __launch_bounds__(512) void conv_w_kernel(
    const float* __restrict__ W, const float* __restrict__ lA,
    const float* __restrict__ lB, unsigned short* __restrict__ Wb) {
    const int nb = blockIdx.x * 4;        // 1024 blocks
    const int k0 = threadIdx.x * 8;       // 512 thr * 8 = 4096

    float acc[4][8];
#pragma unroll
    for (int r = 0; r < 4; ++r) {
        const float4* w4 = (const float4*)(W + (size_t)(nb + r) * K_DIM + k0);
        float4 v0 = w4[0], v1 = w4[1];
        acc[r][0] = v0.x; acc[r][1] = v0.y; acc[r][2] = v0.z; acc[r][3] = v0.w;
        acc[r][4] = v1.x; acc[r][5] = v1.y; acc[r][6] = v1.z; acc[r][7] = v1.w;
    }
    float brs[4][16];
#pragma unroll
    for (int r = 0; r < 4; ++r)
#pragma unroll
        for (int t = 0; t < 16; ++t) brs[r][t] = lB[(size_t)(nb + r) * 16 + t];

#pragma unroll
    for (int t = 0; t < 16; ++t) {
        const float4* a4 = (const float4*)(lA + (size_t)t * K_DIM + k0);
        float4 v0 = a4[0], v1 = a4[1];
        float av[8] = {v0.x, v0.y, v0.z, v0.w, v1.x, v1.y, v1.z, v1.w};
#pragma unroll
        for (int r = 0; r < 4; ++r)
#pragma unroll
            for (int j = 0; j < 8; ++j) acc[r][j] += brs[r][t] * av[j];
    }
#pragma unroll
    for (int r = 0; r < 4; ++r) {
        union { unsigned short us[8]; uint4 v; } u;
#pragma unroll
        for (int j = 0; j < 8; ++j) u.us[j] = f2bf(acc[r][j]);
        *(uint4*)(Wb + (size_t)(nb + r) * K_DIM + k0) = u.v;
    }
}

// --- gemm: 256x256, BK=64, 8 waves, 32x32x16 core, lgkm-pipelined ----------
__global__ __launch_bounds__(512, 2) void gemm_kernel(
    const unsigned short* __restrict__ A,   // [8192][4096] bf16
    const unsigned short* __restrict__ B,   // [4096][4096] bf16 (W')
    const float* __restrict__ bvec, const float* __restrict__ lbvec,
    float* __restrict__ C) {
    const int tid = threadIdx.x;
    const int lane = tid & 63;
    const int wid = tid >> 6;        // 0..7
    const int wr = wid >> 2;         // 0..1  M-half (128 rows)
    const int wc = wid & 3;          // 0..3  N-quarter (64 cols)

    // XCD-column-resident mapping (R7)
    const int bid = blockIdx.x;
    const int ntile = (bid & 7) * 2 + ((bid >> 3) & 1);  // 0..15
    const int mtile = bid >> 4;                          // 0..31
    const int m0 = mtile * 256, n0 = ntile * 256;

    __shared__ __align__(16) unsigned short ldsA[2 * 2 * 128 * 64];  // 64 KiB
    __shared__ __align__(16) unsigned short ldsB[2 * 2 * 128 * 64];  // 64 KiB

    // --- staging: linear LDS dest, inverse-swizzled global src (T2) ---
    const int lr8 = lane >> 3;             // 0..7
    const int cch = (lane & 7) ^ lr8;      // swizzled 16B-chunk index
    const unsigned short* aSb = A + (size_t)(m0 + lr8) * K_DIM + cch * 8;
    const unsigned short* bSb = B + (size_t)(n0 + lr8) * K_DIM + cch * 8;

    auto stageA = [&](int par_, int h, int kt) {
#pragma unroll
        for (int s = 0; s < 2; ++s) {
            const int j = wid * 2 + s;
            const unsigned short* g = aSb + (size_t)(h * 128 + j * 8) * K_DIM + kt * 64;
            __builtin_amdgcn_global_load_lds(
                (const __attribute__((address_space(1))) void*)g,
                (__attribute__((address_space(3))) void*)(ldsA + (par_ * 2 + h) * 8192 + j * 512),
                16, 0, 0);
        }
    };
    auto stageB = [&](int par_, int h, int kt) {
#pragma unroll
        for (int s = 0; s < 2; ++s) {
            const int j = wid * 2 + s;
            const unsigned short* g = bSb + (size_t)(h * 128 + j * 8) * K_DIM + kt * 64;
            __builtin_amdgcn_global_load_lds(
                (const __attribute__((address_space(1))) void*)g,
                (__attribute__((address_space(3))) void*)(ldsB + (par_ * 2 + h) * 8192 + j * 512),
                16, 0, 0);
        }
    };
    auto stageTile = [&](int par_, int kt) {   // 8 loads/thread
        stageB(par_, 0, kt); stageB(par_, 1, kt);
        stageA(par_, 0, kt); stageA(par_, 1, kt);
    };

    // --- read side: 32x32x16 fragments. row=lane&31, k=(lane>>5)*8+j.
    //     byte = row*128 + ((ks*32 + (lane>>5)*16) ^ ((row&7)<<4))  [T2]
    const int rowA = (lane & 31);
    const int swz = (lane & 7) << 4;
    const int kbase = (lane >> 5) * 16;    // byte offset within k-row

    auto readA32 = [&](int par_, int mf, int ks) -> bf16x8 {
        const int row = mf * 32 + rowA;    // within 128-row half (wr)
        const char* p = (const char*)(ldsA + (par_ * 2 + wr) * 8192) +
                        row * 128 + ((ks * 32 + kbase) ^ swz);
        return *(const bf16x8*)p;
    };
    auto readB32 = [&](int par_, int nf, int ks) -> bf16x8 {
        const int row = (wc & 1) * 64 + nf * 32 + rowA;  // within 128-row half
        const char* p = (const char*)(ldsB + (par_ * 2 + (wc >> 1)) * 8192) +
                        row * 128 + ((ks * 32 + kbase) ^ swz);
        return *(const bf16x8*)p;
    };

    f32x16 acc[4][2] = {};                 // 128 regs (AGPR-unified)
    bf16x8 sa0[4], sb0[2], sa1[4], sb1[2]; // 2 x 24-reg operand sets

#define READS0(par_, ks) do { \
    _Pragma("unroll") for (int mf = 0; mf < 4; ++mf) sa0[mf] = readA32(par_, mf, ks); \
    _Pragma("unroll") for (int nf = 0; nf < 2; ++nf) sb0[nf] = readB32(par_, nf, ks); } while (0)
#define READS1(par_, ks) do { \
    _Pragma("unroll") for (int mf = 0; mf < 4; ++mf) sa1[mf] = readA32(par_, mf, ks); \
    _Pragma("unroll") for (int nf = 0; nf < 2; ++nf) sb1[nf] = readB32(par_, nf, ks); } while (0)
#define BURST0() do { __builtin_amdgcn_s_setprio(1); \
    _Pragma("unroll") for (int mf = 0; mf < 4; ++mf) \
        _Pragma("unroll") for (int nf = 0; nf < 2; ++nf) \
            acc[mf][nf] = __builtin_amdgcn_mfma_f32_32x32x16_bf16( \
                sa0[mf], sb0[nf], acc[mf][nf], 0, 0, 0); \
    __builtin_amdgcn_s_setprio(0); } while (0)
#define BURST1() do { __builtin_amdgcn_s_setprio(1); \
    _Pragma("unroll") for (int mf = 0; mf < 4; ++mf) \
        _Pragma("unroll") for (int nf = 0; nf < 2; ++nf) \
            acc[mf][nf] = __builtin_amdgcn_mfma_f32_32x32x16_bf16( \
                sa1[mf], sb1[nf], acc[mf][nf], 0, 0, 0); \
    __builtin_amdgcn_s_setprio(0); } while (0)

    // --- prologue: stage t0,t1; drain t0; publish ---
    stageTile(0, 0);
    stageTile(1, 1);
    WAITV8();
    BARRIER();

#pragma unroll 1
    for (int kt = 0; kt < NT; ++kt) {
        const int par = kt & 1;
        // k-step pipeline: reads ks0,ks1 up front; counted lgkm waits.
        READS0(par, 0);
        READS1(par, 1);
        SCHED_FENCE();
        LGKMC(6); SCHED_FENCE();     // ks0 ready (ks1 in flight)
        BURST0();
        READS0(par, 2);
        SCHED_FENCE();
        LGKMC(6); SCHED_FENCE();     // ks1 ready (ks2 in flight)
        BURST1();
        READS1(par, 3);
        SCHED_FENCE();
        LGKMC(6); SCHED_FENCE();     // ks2 ready (ks3 in flight)
        BURST0();
        LGKMC(0); SCHED_FENCE();     // ks3 ready
        BURST1();
        BARRIER();                   // all waves done reading tile t
        if (kt + 2 < NT) { stageTile(par, kt + 2); WAITV8(); }
        else { WAITV0(); }
        BARRIER();                   // t+1 published
    }

#undef READS0
#undef READS1
#undef BURST0
#undef BURST1

    // --- epilogue: 32x32 C/D layout (HW-verified): col=lane&31,
    //     row = (r&3) + 8*(r>>2) + 4*(lane>>5). NT stores + fused bias. ---
#pragma unroll
    for (int nf = 0; nf < 2; ++nf) {
        const int gc = n0 + wc * 64 + nf * 32 + (lane & 31);
        const float bv = bvec[gc] + lbvec[gc];
#pragma unroll
        for (int mf = 0; mf < 4; ++mf) {
            const int gr0 = m0 + wr * 128 + mf * 32 + 4 * (lane >> 5);
            f32x16 v = acc[mf][nf];
#pragma unroll
            for (int r = 0; r < 16; ++r) {
                const int row = gr0 + (r & 3) + 8 * (r >> 2);
                __builtin_nontemporal_store(v[r] + bv, &C[(size_t)row * N_DIM + gc]);
            }
        }
    }
}

// --- Fallback: naive fp32 (only if ws too small) ----------------------------
__global__ __launch_bounds__(256) void naive_kernel(
    const float* __restrict__ x, const float* __restrict__ W,
    const float* __restrict__ b, const float* __restrict__ lA,
    const float* __restrict__ lB, const float* __restrict__ lb,
    float* __restrict__ out) {
    __shared__ float xs[K_DIM];
    __shared__ float ts[16];
    const int m = blockIdx.x;
    const int tid = threadIdx.x;
    for (int k = tid; k < K_DIM; k += 256) xs[k] = x[(size_t)m * K_DIM + k];
    if (tid < 16) ts[tid] = 0.f;
    __syncthreads();
    float part[16] = {};
    for (int k = tid * 16; k < tid * 16 + 16; ++k) {
        float xv = xs[k];
#pragma unroll
        for (int r = 0; r < 16; ++r) part[r] += xv * lA[(size_t)r * K_DIM + k];
    }
#pragma unroll
    for (int r = 0; r < 16; ++r) atomicAdd(&ts[r], part[r]);
    __syncthreads();
    const int n = blockIdx.y * 256 + tid;
    float acc = b[n] + lb[n];
#pragma unroll
    for (int r = 0; r < 16; ++r) acc += ts[r] * lB[(size_t)n * 16 + r];
    const float* wrow = W + (size_t)n * K_DIM;
    for (int k = 0; k < K_DIM; ++k) acc += xs[k] * wrow[k];
    out[(size_t)m * N_DIM + n] = acc;
}

// ---------------------------------------------------------------------------
extern "C" void kernel_launch(void* const* d_in, const int* in_sizes, int n_in,
                              void* d_out, int out_size, void* d_ws, size_t ws_size,
                              hipStream_t stream) {
    const float* x  = (const float*)d_in[0];
    const float* W  = (const float*)d_in[1];
    const float* b  = (const float*)d_in[2];
    const float* lA = (const float*)d_in[3];
    const float* lB = (const float*)d_in[4];
    const float* lb = (const float*)d_in[5];
    float* out = (float*)d_out;

    const size_t xb_bytes = (size_t)M_DIM * K_DIM * 2;  // 64 MiB
    const size_t wb_bytes = (size_t)N_DIM * K_DIM * 2;  // 32 MiB

    if (ws_size >= xb_bytes + wb_bytes) {
        unsigned short* xb = (unsigned short*)d_ws;
        unsigned short* wb = (unsigned short*)((char*)d_ws + xb_bytes);

        conv_x_kernel<<<(M_DIM * K_DIM) / (256 * 8), 256, 0, stream>>>(x, xb);
        conv_w_kernel<<<N_DIM / 4, 512, 0, stream>>>(W, lA, lB, wb);

        gemm_kernel<<<(M_DIM / 256) * (N_DIM / 256), 512, 0, stream>>>(xb, wb, b, lb, out);
    } else {
        dim3 grid(M_DIM, N_DIM / 256);
        naive_kernel<<<grid, 256, 0, stream>>>(x, W, b, lA, lB, lb, out);
    }
}

// Round 13
// 304.866 us; speedup vs baseline: 3.4330x; 1.0910x over previous
//
#include <hip/hip_runtime.h>
#include <hip/hip_bf16.h>
#include <stdint.h>

// ---------------------------------------------------------------------------
// LoRALinear: y = x @ (W + B@A)^T + (b + lora_bias)
// M=8192, N=4096, K=4096.
// R13: faithful m201 8-phase port (16x16x32 core, conflicts=0 swizzle):
//  - NO sched_barrier walls: plain lgkmcnt(0) after each barrier; compiler
//    free to hide stage/addr VALU under MFMA bursts (R10's walls pinned it).
//  - staggered 2-loads/phase staging: p1/p2 stage A-halves of t+1 (par^1),
//    p3/p4 stage B-halves of t+2 (par). Each lands after its region's last
//    reader phase + barrier (A(par^1) free since t-1's p3; B(par) since p2).
//  - counted vmcnt(4) once per KT at p4: ledger = 12 outstanding -> drains
//    exactly {A(t+1),B(t+1)}, leaves B(t+2) in flight. Tail: vmcnt(0).
//  - optional lgkmcnt(8) before p1's barrier (12 reads in flight).
// R4/R11 lesson: ~250 regs/wave cap; acc[8][4] only.
// R5 lesson: publication = drain-then-barrier before cross-wave LDS reads.
// R12 lesson: 32x32 frags conflict with 8-row swizzle; 16x16x32 stays clean.
// ---------------------------------------------------------------------------

#define M_DIM 8192
#define N_DIM 4096
#define K_DIM 4096
#define NT    (K_DIM / 64)   // 64 K-tiles

typedef __attribute__((ext_vector_type(8))) short bf16x8;
typedef __attribute__((ext_vector_type(4))) float f32x4;

#define BARRIER() __builtin_amdgcn_s_barrier()
#define WAITV8() asm volatile("s_waitcnt vmcnt(8)" ::: "memory")
#define WAITV4() asm volatile("s_waitcnt vmcnt(4)" ::: "memory")
#define WAITV0() asm volatile("s_waitcnt vmcnt(0)" ::: "memory")
#define LGKM0()  asm volatile("s_waitcnt lgkmcnt(0)" ::: "memory")
#define LGKM8()  asm volatile("s_waitcnt lgkmcnt(8)" ::: "memory")

static __device__ __forceinline__ unsigned short f2bf(float f) {
    unsigned int u = __builtin_bit_cast(unsigned int, f);
    unsigned int r = (u + 0x7fffu + ((u >> 16) & 1u)) >> 16;
    return (unsigned short)r;
}

// --- conv_x: bf16(x) --------------------------------------------------------
__global__ __launch_bounds__(256) void conv_x_kernel(
    const float* __restrict__ x, unsigned short* __restrict__ xb) {
    size_t i = ((size_t)blockIdx.x * 256 + threadIdx.x) * 8;
    float4 a = *(const float4*)(x + i);
    float4 c = *(const float4*)(x + i + 4);
    union { unsigned short us[8]; uint4 v; } u;
    u.us[0] = f2bf(a.x); u.us[1] = f2bf(a.y); u.us[2] = f2bf(a.z); u.us[3] = f2bf(a.w);
    u.us[4] = f2bf(c.x); u.us[5] = f2bf(c.y); u.us[6] = f2bf(c.z); u.us[7] = f2bf(c.w);
    *(uint4*)(xb + i) = u.v;
}

// --- conv_w: bf16(W + B@A). 4 rows/block, lA read once per block. ----------
__global__ __launch_bounds__(512) void conv_w_kernel(
    const float* __restrict__ W, const float* __restrict__ lA,
    const float* __restrict__ lB, unsigned short* __restrict__ Wb) {
    const int nb = blockIdx.x * 4;        // 1024 blocks
    const int k0 = threadIdx.x * 8;       // 512 thr * 8 = 4096

    float acc[4][8];
#pragma unroll
    for (int r = 0; r < 4; ++r) {
        const float4* w4 = (const float4*)(W + (size_t)(nb + r) * K_DIM + k0);
        float4 v0 = w4[0], v1 = w4[1];
        acc[r][0] = v0.x; acc[r][1] = v0.y; acc[r][2] = v0.z; acc[r][3] = v0.w;
        acc[r][4] = v1.x; acc[r][5] = v1.y; acc[r][6] = v1.z; acc[r][7] = v1.w;
    }
    float brs[4][16];
#pragma unroll
    for (int r = 0; r < 4; ++r)
#pragma unroll
        for (int t = 0; t < 16; ++t) brs[r][t] = lB[(size_t)(nb + r) * 16 + t];

#pragma unroll
    for (int t = 0; t < 16; ++t) {
        const float4* a4 = (const float4*)(lA + (size_t)t * K_DIM + k0);
        float4 v0 = a4[0], v1 = a4[1];
        float av[8] = {v0.x, v0.y, v0.z, v0.w, v1.x, v1.y, v1.z, v1.w};
#pragma unroll
        for (int r = 0; r < 4; ++r)
#pragma unroll
            for (int j = 0; j < 8; ++j) acc[r][j] += brs[r][t] * av[j];
    }
#pragma unroll
    for (int r = 0; r < 4; ++r) {
        union { unsigned short us[8]; uint4 v; } u;
#pragma unroll
        for (int j = 0; j < 8; ++j) u.us[j] = f2bf(acc[r][j]);
        *(uint4*)(Wb + (size_t)(nb + r) * K_DIM + k0) = u.v;
    }
}

// --- gemm: 256x256 tile, BK=64, 8 waves, m201 8-phase staggered staging -----
__global__ __launch_bounds__(512, 2) void gemm_kernel(
    const unsigned short* __restrict__ A,   // [8192][4096] bf16
    const unsigned short* __restrict__ B,   // [4096][4096] bf16 (W')
    const float* __restrict__ bvec, const float* __restrict__ lbvec,
    float* __restrict__ C) {
    const int tid = threadIdx.x;
    const int lane = tid & 63;
    const int wid = tid >> 6;        // 0..7
    const int wr = wid >> 2;         // 0..1  M-half (128 rows)
    const int wc = wid & 3;          // 0..3  N-quarter (64 cols)

    // XCD-column-resident mapping (R7)
    const int bid = blockIdx.x;
    const int ntile = (bid & 7) * 2 + ((bid >> 3) & 1);  // 0..15
    const int mtile = bid >> 4;                          // 0..31
    const int m0 = mtile * 256, n0 = ntile * 256;

    __shared__ __align__(16) unsigned short ldsA[2 * 2 * 128 * 64];  // 64 KiB
    __shared__ __align__(16) unsigned short ldsB[2 * 2 * 128 * 64];  // 64 KiB

    // --- staging: linear LDS dest, inverse-swizzled global src (T2) ---
    const int lr8 = lane >> 3;             // 0..7
    const int cch = (lane & 7) ^ lr8;      // swizzled 16B-chunk index
    const unsigned short* aSb = A + (size_t)(m0 + lr8) * K_DIM + cch * 8;
    const unsigned short* bSb = B + (size_t)(n0 + lr8) * K_DIM + cch * 8;

    auto stageA = [&](int par_, int h, int kt) {   // one half-tile = 2 loads
#pragma unroll
        for (int s = 0; s < 2; ++s) {
            const int j = wid * 2 + s;
            const unsigned short* g = aSb + (size_t)(h * 128 + j * 8) * K_DIM + kt * 64;
            __builtin_amdgcn_global_load_lds(
                (const __attribute__((address_space(1))) void*)g,
                (__attribute__((address_space(3))) void*)(ldsA + (par_ * 2 + h) * 8192 + j * 512),
                16, 0, 0);
        }
    };
    auto stageB = [&](int par_, int h, int kt) {
#pragma unroll
        for (int s = 0; s < 2; ++s) {
            const int j = wid * 2 + s;
            const unsigned short* g = bSb + (size_t)(h * 128 + j * 8) * K_DIM + kt * 64;
            __builtin_amdgcn_global_load_lds(
                (const __attribute__((address_space(1))) void*)g,
                (__attribute__((address_space(3))) void*)(ldsB + (par_ * 2 + h) * 8192 + j * 512),
                16, 0, 0);
        }
    };

    // --- read side (T2 swizzle) ---
    const int rowByte = (lane & 15) * 128;
    const int swz = (lane & 7) << 4;
    const int kc0 = (0 * 64 + (lane >> 4) * 16) ^ swz;
    const int kc1 = (1 * 64 + (lane >> 4) * 16) ^ swz;
    const int baseBoff = (wc & 1) * 4096;

    auto readA = [&](int par_, int mf, int kk) -> bf16x8 {
        const char* p = (const char*)(ldsA + (par_ * 2 + wr) * 8192 + mf * 1024) +
                        rowByte + (kk ? kc1 : kc0);
        return *(const bf16x8*)p;
    };
    auto readB = [&](int par_, int nf, int kk) -> bf16x8 {
        const char* p = (const char*)(ldsB + (par_ * 2 + (wc >> 1)) * 8192 + baseBoff + nf * 1024) +
                        rowByte + (kk ? kc1 : kc0);
        return *(const bf16x8*)p;
    };

    f32x4 acc[8][4] = {};
    bf16x8 a[4][2], b[4][2];

    auto mfmaQ = [&](int qm, int qn) {   // 16 MFMA: 4 mf x 2 nf x 2 kk
#pragma unroll
        for (int i = 0; i < 4; ++i)
#pragma unroll
            for (int jn = 0; jn < 2; ++jn)
#pragma unroll
                for (int kk = 0; kk < 2; ++kk)
                    acc[qm * 4 + i][qn * 2 + jn] = __builtin_amdgcn_mfma_f32_16x16x32_bf16(
                        a[i][kk], b[qn * 2 + jn][kk], acc[qm * 4 + i][qn * 2 + jn], 0, 0, 0);
    };

    // --- prologue: issue in ledger order A(0),B(0),A(1),B(1); drain t0 ---
    stageA(0, 0, 0); stageA(0, 1, 0); stageB(0, 0, 0); stageB(0, 1, 0);
    stageA(1, 0, 1); stageA(1, 1, 1); stageB(1, 0, 1); stageB(1, 1, 1);
    WAITV8();               // t0's 8 drained; t1's 8 in flight
    BARRIER();              // publish t0

    // Per K-tile: p1: 12 reads + stageA(t+1,h0)   p2: 4 reads + stageA(t+1,h1)
    //             p3: 8 reads + stageB(t+2,h0)    p4: stageB(t+2,h1) + vmcnt(4)
#define KTILE(kt, par)                                                          \
    {                                                                           \
        /* p1 */                                                                \
        _Pragma("unroll") for (int i = 0; i < 4; ++i)                           \
            _Pragma("unroll") for (int kk = 0; kk < 2; ++kk)                    \
                a[i][kk] = readA(par, i, kk);                                    \
        _Pragma("unroll") for (int nf = 0; nf < 2; ++nf)                        \
            _Pragma("unroll") for (int kk = 0; kk < 2; ++kk)                    \
                b[nf][kk] = readB(par, nf, kk);                                  \
        if ((kt) >= 1 && (kt) + 1 < NT) stageA((par) ^ 1, 0, (kt) + 1);         \
        LGKM8();                                                                \
        BARRIER();                                                              \
        LGKM0();                                                                \
        __builtin_amdgcn_s_setprio(1); mfmaQ(0, 0); __builtin_amdgcn_s_setprio(0); \
        BARRIER();                                                              \
        /* p2 */                                                                \
        _Pragma("unroll") for (int nf = 2; nf < 4; ++nf)                        \
            _Pragma("unroll") for (int kk = 0; kk < 2; ++kk)                    \
                b[nf][kk] = readB(par, nf, kk);                                  \
        if ((kt) >= 1 && (kt) + 1 < NT) stageA((par) ^ 1, 1, (kt) + 1);         \
        BARRIER();                                                              \
        LGKM0();                                                                \
        __builtin_amdgcn_s_setprio(1); mfmaQ(0, 1); __builtin_amdgcn_s_setprio(0); \
        BARRIER();                                                              \
        /* p3 (B(par) last read at p2 -> safe to overwrite for t+2) */          \
        _Pragma("unroll") for (int i = 0; i < 4; ++i)                           \
            _Pragma("unroll") for (int kk = 0; kk < 2; ++kk)                    \
                a[i][kk] = readA(par, 4 + i, kk);                                \
        if ((kt) + 2 < NT) stageB(par, 0, (kt) + 2);                            \
        BARRIER();                                                              \
        LGKM0();                                                                \
        __builtin_amdgcn_s_setprio(1); mfmaQ(1, 0); __builtin_amdgcn_s_setprio(0); \
        BARRIER();                                                              \
        /* p4: ledger = 12 outstanding; vmcnt(4) drains {A(t+1),B(t+1)} */      \
        if ((kt) + 2 < NT) { stageB(par, 1, (kt) + 2); WAITV4(); }              \
        else { WAITV0(); }                                                      \
        BARRIER();                                                              \
        __builtin_amdgcn_s_setprio(1); mfmaQ(1, 1); __builtin_amdgcn_s_setprio(0); \
        BARRIER();                                                              \
    }

#pragma unroll 1
    for (int kt = 0; kt < NT; kt += 2) {
        KTILE(kt, 0);
        KTILE(kt + 1, 1);
    }
#undef KTILE

    // --- epilogue: C = acc + (b + lora_bias); NT stores ---
#pragma unroll
    for (int nf = 0; nf < 4; ++nf) {
        const int gc = n0 + wc * 64 + nf * 16 + (lane & 15);
        const float bv = bvec[gc] + lbvec[gc];
#pragma unroll
        for (int mf = 0; mf < 8; ++mf) {
            const int gr0 = m0 + wr * 128 + mf * 16 + (lane >> 4) * 4;
            f32x4 v = acc[mf][nf];
#pragma unroll
            for (int j = 0; j < 4; ++j)
                __builtin_nontemporal_store(v[j] + bv, &C[(size_t)(gr0 + j) * N_DIM + gc]);
        }
    }
}

// --- Fallback: naive fp32 (only if ws too small) ----------------------------
__global__ __launch_bounds__(256) void naive_kernel(
    const float* __restrict__ x, const float* __restrict__ W,
    const float* __restrict__ b, const float* __restrict__ lA,
    const float* __restrict__ lB, const float* __restrict__ lb,
    float* __restrict__ out) {
    __shared__ float xs[K_DIM];
    __shared__ float ts[16];
    const int m = blockIdx.x;
    const int tid = threadIdx.x;
    for (int k = tid; k < K_DIM; k += 256) xs[k] = x[(size_t)m * K_DIM + k];
    if (tid < 16) ts[tid] = 0.f;
    __syncthreads();
    float part[16] = {};
    for (int k = tid * 16; k < tid * 16 + 16; ++k) {
        float xv = xs[k];
#pragma unroll
        for (int r = 0; r < 16; ++r) part[r] += xv * lA[(size_t)r * K_DIM + k];
    }
#pragma unroll
    for (int r = 0; r < 16; ++r) atomicAdd(&ts[r], part[r]);
    __syncthreads();
    const int n = blockIdx.y * 256 + tid;
    float acc = b[n] + lb[n];
#pragma unroll
    for (int r = 0; r < 16; ++r) acc += ts[r] * lB[(size_t)n * 16 + r];
    const float* wrow = W + (size_t)n * K_DIM;
    for (int k = 0; k < K_DIM; ++k) acc += xs[k] * wrow[k];
    out[(size_t)m * N_DIM + n] = acc;
}

// ---------------------------------------------------------------------------
extern "C" void kernel_launch(void* const* d_in, const int* in_sizes, int n_in,
                              void* d_out, int out_size, void* d_ws, size_t ws_size,
                              hipStream_t stream) {
    const float* x  = (const float*)d_in[0];
    const float* W  = (const float*)d_in[1];
    const float* b  = (const float*)d_in[2];
    const float* lA = (const float*)d_in[3];
    const float* lB = (const float*)d_in[4];
    const float* lb = (const float*)d_in[5];
    float* out = (float*)d_out;

    const size_t xb_bytes = (size_t)M_DIM * K_DIM * 2;  // 64 MiB
    const size_t wb_bytes = (size_t)N_DIM * K_DIM * 2;  // 32 MiB

    if (ws_size >= xb_bytes + wb_bytes) {
        unsigned short* xb = (unsigned short*)d_ws;
        unsigned short* wb = (unsigned short*)((char*)d_ws + xb_bytes);

        conv_x_kernel<<<(M_DIM * K_DIM) / (256 * 8), 256, 0, stream>>>(x, xb);
        conv_w_kernel<<<N_DIM / 4, 512, 0, stream>>>(W, lA, lB, wb);

        gemm_kernel<<<(M_DIM / 256) * (N_DIM / 256), 512, 0, stream>>>(xb, wb, b, lb, out);
    } else {
        dim3 grid(M_DIM, N_DIM / 256);
        naive_kernel<<<grid, 256, 0, stream>>>(x, W, b, lA, lB, lb, out);
    }
}